// Round 3
// baseline (398.274 us; speedup 1.0000x reference)
//
#include <hip/hip_runtime.h>
#include <math.h>

#define C_      22      // NUM_CLASSES
#define SKIP_   20
#define NSTEP_  200
#define STEP_   4.0f
#define INL_T_  0.9f
#define LAB_T_  500
#define B_      2
#define H_      480
#define W_      640
#define HW_     (H_ * W_)       // 307200
#define P_      (HW_ / SKIP_)   // 15360

#define TS_       64            // spatial tile side
#define TILES_X_  (W_ / TS_)    // 10
#define NTILES_Y_ 8             // covers y 0..511 (cyr<=479 keeps in-bounds)
#define NTILES_   (TILES_X_ * NTILES_Y_)   // 80
#define NPLANES_  (B_ * (C_ - 1))          // 42 live planes (c=0 dead)
#define NPT_      (NPLANES_ * NTILES_)     // 3360 plane-tiles
#define CAP_      2048                     // records per plane-tile

#define SUB_A_    8                        // ray segments per point
#define SEG_LEN_  (NSTEP_ / SUB_A_)        // 25
#define PA_BLOCKS_    ((B_ * P_ * SUB_A_) / 256)  // 960 ray units
#define HIST_BLOCKS_  ((B_ * HW_) / (256 * 4))    // 600 histogram units (int4/thread)
#define UNITS1_       (PA_BLOCKS_ + HIST_BLOCKS_) // 1560
#define GRID1_        1024                 // co-resident guaranteed via __launch_bounds__(256,4)
#define INL_BLOCKS_   ((B_ * P_) / 256)    // 120

#define KEY_INIT_ 0x00000000FFFFFFFFull    // (count 0, idx 0) under the key encoding
#define MAGIC1_   0x9E3779B9u
#define MAGIC2_   0x61C8C646u              // == ~MAGIC1_  (pair unsatisfiable by uniform poison)

// -------- shared helper: ray->tile-run record emit --------
__device__ __forceinline__ void emit_run(unsigned int* cnt, uint4* lists, int pt,
                                         int xi, int yi, int i0, int i1,
                                         float dnx, float dny) {
    unsigned slot = atomicAdd(&cnt[pt], 1u);
    if (slot < CAP_) {
        uint4 r;
        r.x = (unsigned)xi | ((unsigned)yi << 16);
        r.y = (unsigned)i0 | ((unsigned)i1 << 8);
        r.z = __float_as_uint(dnx);
        r.w = __float_as_uint(dny);
        lists[(size_t)pt * CAP_ + slot] = r;
    }
}

// ============================================================================
// Kernel 1: block 0 zeroes workspace + releases flag gate; all 1024 blocks
// then grid-stride over {960 ray-binning units, 600 histogram units}.
// Deadlock-free: GRID1_=1024 blocks all co-resident (__launch_bounds__(256,4)
// guarantees >=4 blocks/CU x 256 CUs), so block 0 always makes progress.
// ============================================================================
__global__ __launch_bounds__(256, 4) void binray_init_kernel(const int* __restrict__ label,
                                                             const float* __restrict__ vp,
                                                             unsigned int* __restrict__ cnt,
                                                             uint4* __restrict__ lists,
                                                             int* __restrict__ counts,
                                                             float* __restrict__ z_sum,
                                                             float* __restrict__ n_inl,
                                                             unsigned int* __restrict__ done,
                                                             unsigned int* __restrict__ rdone,
                                                             unsigned int* __restrict__ flags,
                                                             unsigned long long* __restrict__ key) {
    __shared__ int h[C_];
    const int tid = threadIdx.x;
    if (blockIdx.x == 0) {
        // ---- zero/init all small state ----
        for (int i = tid; i < NPT_; i += 256) cnt[i] = 0u;
        if (tid < B_ * C_) {
            counts[tid] = 0;
            z_sum[tid] = 0.0f;
            n_inl[tid] = 0.0f;
            key[tid] = KEY_INIT_;
        }
        if (tid == 0) { *done = 0u; *rdone = 0u; }
        __syncthreads();
        __threadfence();                       // release zeroed state device-wide
        if (tid == 0) {
            atomicExch(&flags[0], MAGIC1_);
            atomicExch(&flags[1], MAGIC2_);
        }
        __syncthreads();
    } else {
        // ---- gate: wait for init (conjunction cannot be pre-satisfied by poison) ----
        if (tid == 0) {
            while (true) {
                unsigned f1 = atomicAdd(&flags[0], 0u);
                unsigned f2 = atomicAdd(&flags[1], 0u);
                if (f1 == MAGIC1_ && f2 == MAGIC2_) break;
                __builtin_amdgcn_s_sleep(2);
            }
            __threadfence();                   // acquire
        }
        __syncthreads();
    }

    for (int u = blockIdx.x; u < UNITS1_; u += GRID1_) {
        if (u < PA_BLOCKS_) {
            // ---- ray->tile-run binning ----
            int t0  = u * 256 + tid;             // 0 .. B_*P_*SUB_A_-1
            int pt  = t0 >> 3;                   // point id
            int sub = t0 & 7;
            int b   = pt / P_;
            int pi  = pt - b * P_;
            int idx = pi * SKIP_;
            int lab = label[b * HW_ + idx];
            if (lab > 0) {
                int xi = idx % W_, yi = idx / W_;
                float xs = (float)xi, ys = (float)yi;
                const float* s = vp + ((size_t)(b * HW_ + idx) * (C_ * 3)) + lab * 3;
                float dx = s[0], dy = s[1];
                float nrm = sqrtf(__fadd_rn(__fmul_rn(dx, dx), __fmul_rn(dy, dy))) + 1e-9f;
                float dnx = dx / nrm, dny = dy / nrm;
                int base = (b * (C_ - 1) + (lab - 1)) * NTILES_;
                int curTile = -1, runStart = 0;
                bool entered = false;
                int iBeg = sub * SEG_LEN_, iEnd = iBeg + SEG_LEN_;
                for (int i = iBeg; i < iEnd; ++i) {
                    float t = (float)(i + 1) * STEP_;
                    float cx = __fadd_rn(xs, __fmul_rn(dnx, t));   // mul-then-add, no fma
                    float cy = __fadd_rn(ys, __fmul_rn(dny, t));
                    float cxr = rintf(cx);                          // round-half-even == jnp.round
                    float cyr = rintf(cy);
                    int tl2 = -1;
                    if (cxr >= 0.0f && cxr <= (float)(W_ - 1) && cyr >= 0.0f && cyr <= (float)(H_ - 1))
                        tl2 = (((int)cyr) >> 6) * TILES_X_ + (((int)cxr) >> 6);
                    if (tl2 != curTile) {
                        if (curTile >= 0)
                            emit_run(cnt, lists, base + curTile, xi, yi, runStart, i - 1, dnx, dny);
                        curTile = tl2;
                        runStart = i;
                    }
                    if (tl2 >= 0) entered = true;
                    else if (entered) break;   // in-bounds i-set is an interval
                }
                if (curTile >= 0)
                    emit_run(cnt, lists, base + curTile, xi, yi, runStart, iEnd - 1, dnx, dny);
            }
        } else {
            // ---- label histogram, int4-vectorized ----
            int cb  = u - PA_BLOCKS_;
            const int bpb = HW_ / 1024;          // 300 units per image
            int b   = cb / bpb;
            int off = (cb % bpb) * 1024 + tid * 4;
            if (tid < C_) h[tid] = 0;
            __syncthreads();
            int4 l4 = *(const int4*)(label + b * HW_ + off);
            atomicAdd(&h[l4.x], 1);
            atomicAdd(&h[l4.y], 1);
            atomicAdd(&h[l4.z], 1);
            atomicAdd(&h[l4.w], 1);
            __syncthreads();
            if (tid < C_) {
                int v = h[tid];
                if (v) atomicAdd(&counts[b * C_ + tid], v);
            }
            __syncthreads();   // protect h before next stride iteration
        }
    }
}

// ============================================================================
// Kernel 2: blocks [0,NPT_) rasterize+argmax (signal rdone); blocks
// [NPT_,NPT_+INL_BLOCKS_) spin on rdone (120 spinners << guaranteed-resident
// slots -> deadlock-free under any dispatch order), then inlier accumulate;
// the last inlier block finalizes rois+pose and re-arms the flag gate.
// key = (count << 32) | (0xFFFFFFFF - idx): max key == max count, tie -> min idx.
// ============================================================================
__global__ __launch_bounds__(256) void raster_inlier_finalize_kernel(
        const unsigned int* __restrict__ cnt, const uint4* __restrict__ lists,
        unsigned long long* __restrict__ key,
        const int* __restrict__ label, const float* __restrict__ vp,
        float* __restrict__ z_sum, float* __restrict__ n_inl,
        int* __restrict__ counts, const float* __restrict__ extents,
        const float* __restrict__ meta,
        unsigned int* __restrict__ done, unsigned int* __restrict__ rdone,
        unsigned int* __restrict__ flags, float* __restrict__ out) {
    __shared__ union {
        struct { unsigned int tile[TS_ * TS_ / 2]; unsigned int sv[256]; int si[256]; } rb;  // 10.25 KB
        struct { float zs[C_]; float ns[C_]; unsigned long long kk[C_]; int last_flag; } in;
    } sm;
    const int tid = threadIdx.x;

    if (blockIdx.x < NPT_) {
        // -------- raster + argmax for one plane-tile --------
        int pt = blockIdx.x;
        int n = (int)cnt[pt];
        if (n == 0) {                       // empty: cannot beat key init
            if (tid == 0) atomicAdd(rdone, 1u);
            return;
        }
        if (n > CAP_) n = CAP_;
        {   // zero tile with uint4 stores (2 per thread)
            uint4* t4 = (uint4*)sm.rb.tile;
            t4[tid]       = make_uint4(0u, 0u, 0u, 0u);
            t4[tid + 256] = make_uint4(0u, 0u, 0u, 0u);
        }
        __syncthreads();
        int p  = pt / NTILES_;
        int tl = pt % NTILES_;
        int b = p / (C_ - 1);
        int c = p % (C_ - 1) + 1;
        int x0 = (tl % TILES_X_) * TS_;
        int y0 = (tl / TILES_X_) * TS_;
        const uint4* lst = lists + (size_t)pt * CAP_;
        int hwv = tid >> 5, ln = tid & 31;   // half-wave per record
        for (int r = hwv; r < n; r += 8) {
            uint4 rec = lst[r];
            int i0 = (int)(rec.y & 0xFFu), i1 = (int)((rec.y >> 8) & 0xFFu);
            float xs = (float)(rec.x & 0xFFFFu);
            float ys = (float)(rec.x >> 16);
            float dnx = __uint_as_float(rec.z);
            float dny = __uint_as_float(rec.w);
            for (int i = i0 + ln; i <= i1; i += 32) {
                float t = (float)(i + 1) * STEP_;
                float cx = __fadd_rn(xs, __fmul_rn(dnx, t));   // identical ops as pass A
                float cy = __fadd_rn(ys, __fmul_rn(dny, t));
                int lx = (int)rintf(cx) - x0;
                int ly = (int)rintf(cy) - y0;
                int cell = ly * TS_ + lx;                      // in-tile by construction
                atomicAdd(&sm.rb.tile[cell >> 1], 1u << ((cell & 1) * 16));
            }
        }
        __syncthreads();
        // conflict-free strided scan: word ix = tid + 256*j (bank = tid%32)
        unsigned bv = 0u; int bi = 0;
        {
            unsigned w0 = sm.rb.tile[tid];
            bv = w0 & 0xFFFFu; bi = tid * 2;
            unsigned hi = w0 >> 16;
            if (hi > bv) { bv = hi; bi = tid * 2 + 1; }
        }
        #pragma unroll
        for (int j = 1; j < 8; ++j) {
            int ix = tid + j * 256;
            unsigned w = sm.rb.tile[ix];
            unsigned lo = w & 0xFFFFu, hi = w >> 16;
            if (lo > bv) { bv = lo; bi = ix * 2; }
            if (hi > bv) { bv = hi; bi = ix * 2 + 1; }
        }
        sm.rb.sv[tid] = bv; sm.rb.si[tid] = bi;
        __syncthreads();
        for (int s = 128; s > 0; s >>= 1) {
            if (tid < s) {
                unsigned ov = sm.rb.sv[tid + s]; int oi = sm.rb.si[tid + s];
                if (ov > sm.rb.sv[tid] || (ov == sm.rb.sv[tid] && oi < sm.rb.si[tid])) {
                    sm.rb.sv[tid] = ov; sm.rb.si[tid] = oi;
                }
            }
            __syncthreads();
        }
        if (tid == 0) {
            int ly = sm.rb.si[0] >> 6, lx = sm.rb.si[0] & 63;
            unsigned gidx = (unsigned)((y0 + ly) * W_ + (x0 + lx));
            unsigned long long k = ((unsigned long long)sm.rb.sv[0] << 32)
                                 | (unsigned long long)(0xFFFFFFFFu - gidx);
            atomicMax(&key[b * C_ + c], k);
            __threadfence();                 // release before completion signal
            atomicAdd(rdone, 1u);
        }
        return;
    }

    // -------- inlier accumulation (after all raster blocks signal) --------
    int ib = blockIdx.x - NPT_;
    const int bpb = P_ / 256;
    int b  = ib / bpb;
    int pi = (ib % bpb) * 256 + tid;
    if (tid == 0) {
        while (atomicAdd(rdone, 0u) < (unsigned)NPT_) __builtin_amdgcn_s_sleep(8);
        __threadfence();                     // acquire raster results
    }
    __syncthreads();
    if (tid < C_) {
        sm.in.zs[tid] = 0.0f; sm.in.ns[tid] = 0.0f;
        sm.in.kk[tid] = atomicAdd(&key[b * C_ + tid], 0ull);   // device-scope read
    }
    __syncthreads();
    int idx = pi * SKIP_;
    int lab = label[b * HW_ + idx];
    if (lab > 0) {
        float ys = (float)(idx / W_);
        float xs = (float)(idx % W_);
        const float* s = vp + ((size_t)(b * HW_ + idx) * (C_ * 3)) + lab * 3;
        float dx = s[0], dy = s[1], z = s[2];
        float nrm = sqrtf(__fadd_rn(__fmul_rn(dx, dx), __fmul_rn(dy, dy))) + 1e-9f;
        float dnx = dx / nrm, dny = dy / nrm;
        unsigned long long k = sm.in.kk[lab];
        int pkv = (int)(0xFFFFFFFFu - (unsigned int)(k & 0xFFFFFFFFull));
        float pkx = (float)(pkv % W_), pky = (float)(pkv / W_);
        float dvx = __fsub_rn(pkx, xs), dvy = __fsub_rn(pky, ys);
        float nrm2 = sqrtf(__fadd_rn(__fmul_rn(dvx, dvx), __fmul_rn(dvy, dvy))) + 1e-9f;
        dvx /= nrm2; dvy /= nrm2;
        float dot = __fadd_rn(__fmul_rn(dnx, dvx), __fmul_rn(dny, dvy));
        if (dot > INL_T_) {
            atomicAdd(&sm.in.zs[lab], z);
            atomicAdd(&sm.in.ns[lab], 1.0f);
        }
    }
    __syncthreads();
    if (tid < C_) {
        if (sm.in.ns[tid] != 0.0f) {
            atomicAdd(&z_sum[b * C_ + tid], sm.in.zs[tid]);
            atomicAdd(&n_inl[b * C_ + tid], sm.in.ns[tid]);
        }
    }
    // ---- completion count: last inlier block runs finalize ----
    if (tid == 0) {
        __threadfence();   // release our z_sum/n_inl contributions
        unsigned prev = atomicAdd(done, 1u);
        sm.in.last_flag = (prev == (unsigned)(INL_BLOCKS_ - 1)) ? 1 : 0;
    }
    __syncthreads();
    if (!sm.in.last_flag) return;
    __threadfence();       // acquire all other blocks' contributions
    if (tid == 0) {        // re-arm init gate for next iteration (with or without re-poison)
        atomicExch(&flags[0], 0u);
        atomicExch(&flags[1], 0u);
    }
    int t = tid;
    if (t >= B_ * C_) return;
    int bb = t / C_, c = t % C_;
    float* o = out + t * 14;
    // device-scope atomic reads: avoid any stale-cache hazard across XCDs
    int   cnt_t  = atomicAdd(&counts[t], 0);
    float zsum_t = atomicAdd(&z_sum[t], 0.0f);
    float ninl_t = atomicAdd(&n_inl[t], 0.0f);
    unsigned long long k = atomicAdd(&key[t], 0ull);
    bool valid = (cnt_t >= LAB_T_) && (c > 0);
    if (!valid) {
        #pragma unroll
        for (int k2 = 0; k2 < 14; ++k2) o[k2] = 0.0f;
        return;
    }
    float depth = zsum_t / fmaxf(ninl_t, 1.0f);
    float z_safe = (fabsf(depth) > 0.001f) ? depth : 1.0f;
    float fx = meta[bb * 48 + 0];
    float fy = meta[bb * 48 + 4];
    const float* e = extents + c * 3;
    float diam = sqrtf(e[0]*e[0] + e[1]*e[1] + e[2]*e[2]);
    float vmax = (float)(unsigned int)(k >> 32);
    int pkv = (int)(0xFFFFFFFFu - (unsigned int)(k & 0xFFFFFFFFull));
    float pkx = (float)(pkv % W_), pky = (float)(pkv / W_);
    float half_w = ((0.5f * diam) * fx) / z_safe;
    float half_h = ((0.5f * diam) * fy) / z_safe;
    o[0] = (float)bb;
    o[1] = (float)c;
    o[2] = pkx - half_w;
    o[3] = pky - half_h;
    o[4] = pkx + half_w;
    o[5] = pky + half_h;
    o[6] = vmax;
    const float* Ki = meta + bb * 48 + 9;   // Kinv row-major 3x3
    float rx = Ki[0]*pkx + Ki[1]*pky + Ki[2];
    float ry = Ki[3]*pkx + Ki[4]*pky + Ki[5];
    float rz = Ki[6]*pkx + Ki[7]*pky + Ki[8];
    o[7]  = 1.0f;
    o[8]  = 0.0f;
    o[9]  = 0.0f;
    o[10] = 0.0f;
    o[11] = depth * rx;
    o[12] = depth * ry;
    o[13] = depth * rz;
}

extern "C" void kernel_launch(void* const* d_in, const int* in_sizes, int n_in,
                              void* d_out, int out_size, void* d_ws, size_t ws_size,
                              hipStream_t stream) {
    const int*   label   = (const int*)d_in[0];    // (B,H,W) int32
    const float* vp      = (const float*)d_in[1];  // (B,H,W,66) f32
    const float* extents = (const float*)d_in[2];  // (22,3) f32
    const float* meta    = (const float*)d_in[4];  // (B,48) f32
    float* out = (float*)d_out;                    // (B,C,14) = 616 f32

    char* ws = (char*)d_ws;
    size_t off = 0;
    unsigned int* cnt = (unsigned int*)(ws + off);  off += NPT_ * sizeof(unsigned int);   // 13440
    int*   counts = (int*)(ws + off);   off += B_ * C_ * sizeof(int);                     // +176
    float* z_sum  = (float*)(ws + off); off += B_ * C_ * sizeof(float);                   // +176
    float* n_inl  = (float*)(ws + off); off += B_ * C_ * sizeof(float);                   // +176
    unsigned int* done  = (unsigned int*)(ws + off); off += sizeof(unsigned int);         // +4
    unsigned int* rdone = (unsigned int*)(ws + off); off += sizeof(unsigned int);         // +4
    unsigned int* flags = (unsigned int*)(ws + off); off += 2 * sizeof(unsigned int);     // +8 (NOT zeroed by k1)
    off = (off + 15) & ~(size_t)15;                 // align 16
    unsigned long long* key = (unsigned long long*)(ws + off);  // init'd by k1 block 0
    off += B_ * C_ * sizeof(unsigned long long);
    off = (off + 15) & ~(size_t)15;
    uint4* lists = (uint4*)(ws + off);              // 3360*2048*16B = 110 MB (uninitialized ok)

    binray_init_kernel<<<GRID1_, 256, 0, stream>>>(label, vp, cnt, lists, counts,
                                                   z_sum, n_inl, done, rdone, flags, key);
    raster_inlier_finalize_kernel<<<NPT_ + INL_BLOCKS_, 256, 0, stream>>>(
        cnt, lists, key, label, vp, z_sum, n_inl, counts, extents, meta,
        done, rdone, flags, out);
}

// Round 4
// 380.479 us; speedup vs baseline: 1.0468x; 1.0468x over previous
//
#include <hip/hip_runtime.h>
#include <math.h>

#define C_      22      // NUM_CLASSES
#define SKIP_   20
#define NSTEP_  200
#define STEP_   4.0f
#define INL_T_  0.9f
#define LAB_T_  500
#define B_      2
#define H_      480
#define W_      640
#define HW_     (H_ * W_)       // 307200
#define P_      (HW_ / SKIP_)   // 15360

#define TS_       64            // spatial tile side
#define TILES_X_  (W_ / TS_)    // 10
#define NTILES_Y_ 8             // covers y 0..511 (cyr<=479 keeps in-bounds)
#define NTILES_   (TILES_X_ * NTILES_Y_)   // 80
#define NPLANES_  (B_ * (C_ - 1))          // 42 live planes (c=0 dead)
#define NPT_      (NPLANES_ * NTILES_)     // 3360 plane-tiles
#define CAP_      2048                     // records per plane-tile

#define SUB_A_    8                        // ray segments per point
#define SEG_LEN_  (NSTEP_ / SUB_A_)        // 25
#define PA_BLOCKS_    ((B_ * P_ * SUB_A_) / 256)  // 960
#define HIST_BLOCKS_  ((B_ * HW_) / (256 * 4))    // 600 (int4 per thread)

#define KEY_INIT_ 0x00000000FFFFFFFFull    // (count 0, idx 0) under the key encoding

// -------- pass A helper: ray->tile-run record emit --------
__device__ __forceinline__ void emit_run(unsigned int* cnt, uint4* lists, int pt,
                                         int xi, int yi, int i0, int i1,
                                         float dnx, float dny) {
    unsigned slot = atomicAdd(&cnt[pt], 1u);
    if (slot < CAP_) {
        uint4 r;
        r.x = (unsigned)xi | ((unsigned)yi << 16);
        r.y = (unsigned)i0 | ((unsigned)i1 << 8);
        r.z = __float_as_uint(dnx);
        r.w = __float_as_uint(dny);
        lists[(size_t)pt * CAP_ + slot] = r;
    }
}

// ============================================================================
// Kernel 1: ray->tile-run binning + per-plane point compaction (sub==0)
//           + label histogram (int4) + key init + out c=0 zeroing.
// ============================================================================
__global__ __launch_bounds__(256) void binray_count_kernel(const int* __restrict__ label,
                                                           const float* __restrict__ vp,
                                                           unsigned int* __restrict__ cnt,
                                                           uint4* __restrict__ lists,
                                                           int* __restrict__ counts,
                                                           unsigned int* __restrict__ cls_cnt,
                                                           uint4* __restrict__ cls,
                                                           unsigned long long* __restrict__ key,
                                                           float* __restrict__ out) {
    if (blockIdx.x < PA_BLOCKS_) {
        int tid = blockIdx.x * 256 + threadIdx.x;   // 0 .. B_*P_*SUB_A_-1
        int pt  = tid >> 3;                          // point id
        int sub = tid & 7;
        int b   = pt / P_;
        int pi  = pt - b * P_;
        int idx = pi * SKIP_;
        int lab = label[b * HW_ + idx];
        if (lab <= 0) return;
        int xi = idx % W_, yi = idx / W_;
        float xs = (float)xi, ys = (float)yi;
        const float* s = vp + ((size_t)(b * HW_ + idx) * (C_ * 3)) + lab * 3;
        float dx = s[0], dy = s[1];
        float nrm = sqrtf(__fadd_rn(__fmul_rn(dx, dx), __fmul_rn(dy, dy))) + 1e-9f;
        float dnx = dx / nrm, dny = dy / nrm;
        int p = b * (C_ - 1) + (lab - 1);
        int base = p * NTILES_;
        if (sub == 0) {
            // compact per-plane point record for the inlier pass
            float z = s[2];
            unsigned slot = atomicAdd(&cls_cnt[p], 1u);
            if (slot < (unsigned)P_) {
                uint4 r;
                r.x = (unsigned)xi | ((unsigned)yi << 16);
                r.y = __float_as_uint(z);
                r.z = __float_as_uint(dnx);
                r.w = __float_as_uint(dny);
                cls[(size_t)p * P_ + slot] = r;
            }
        }
        int curTile = -1, runStart = 0;
        bool entered = false;
        int iBeg = sub * SEG_LEN_, iEnd = iBeg + SEG_LEN_;
        for (int i = iBeg; i < iEnd; ++i) {
            float t = (float)(i + 1) * STEP_;
            float cx = __fadd_rn(xs, __fmul_rn(dnx, t));   // mul-then-add, no fma
            float cy = __fadd_rn(ys, __fmul_rn(dny, t));
            float cxr = rintf(cx);                          // round-half-even == jnp.round
            float cyr = rintf(cy);
            int tl2 = -1;
            if (cxr >= 0.0f && cxr <= (float)(W_ - 1) && cyr >= 0.0f && cyr <= (float)(H_ - 1))
                tl2 = (((int)cyr) >> 6) * TILES_X_ + (((int)cxr) >> 6);
            if (tl2 != curTile) {
                if (curTile >= 0)
                    emit_run(cnt, lists, base + curTile, xi, yi, runStart, i - 1, dnx, dny);
                curTile = tl2;
                runStart = i;
            }
            if (tl2 >= 0) entered = true;
            else if (entered) break;   // in-bounds i-set is an interval (monotone rintf of linear path)
        }
        if (curTile >= 0)
            emit_run(cnt, lists, base + curTile, xi, yi, runStart, iEnd - 1, dnx, dny);
    } else {
        // ---- label histogram, int4-vectorized (+ block 0: key init, out c=0 zero) ----
        __shared__ int h[C_];
        int cb  = blockIdx.x - PA_BLOCKS_;
        if (cb == 0) {
            if (threadIdx.x < B_ * C_)
                key[threadIdx.x] = KEY_INIT_;      // visible to k2 via stream ordering
            else if (threadIdx.x < B_ * C_ + 14)   // out row (b=0,c=0)
                out[threadIdx.x - B_ * C_] = 0.0f;
            else if (threadIdx.x < B_ * C_ + 28)   // out row (b=1,c=0)
                out[C_ * 14 + (threadIdx.x - B_ * C_ - 14)] = 0.0f;
        }
        const int bpb = HW_ / 1024;          // 300 blocks per image
        int b   = cb / bpb;
        int off = (cb % bpb) * 1024 + threadIdx.x * 4;
        if (threadIdx.x < C_) h[threadIdx.x] = 0;
        __syncthreads();
        int4 l4 = *(const int4*)(label + b * HW_ + off);
        atomicAdd(&h[l4.x], 1);
        atomicAdd(&h[l4.y], 1);
        atomicAdd(&h[l4.z], 1);
        atomicAdd(&h[l4.w], 1);
        __syncthreads();
        if (threadIdx.x < C_) {
            int v = h[threadIdx.x];
            if (v) atomicAdd(&counts[b * C_ + threadIdx.x], v);
        }
    }
}

// ============================================================================
// Kernel 2: rasterize + argmax per plane-tile; per-plane last-arriver block
// (done-counter, NO spinning) computes inlier sums from the compact list and
// finalizes that plane's 14 outputs.
// key = (count << 32) | (0xFFFFFFFF - idx): max key == max count, tie -> min idx.
// ============================================================================
__global__ __launch_bounds__(256) void raster_finalize_kernel(
        const unsigned int* __restrict__ cnt, const uint4* __restrict__ lists,
        unsigned long long* __restrict__ key,
        const uint4* __restrict__ cls, const unsigned int* __restrict__ cls_cnt,
        unsigned int* __restrict__ pdone,
        const int* __restrict__ counts, const float* __restrict__ extents,
        const float* __restrict__ meta, float* __restrict__ out) {
    __shared__ union {
        struct { unsigned int tile[TS_ * TS_ / 2]; unsigned int sv[4]; int si[4]; } rb;  // 8.03 KB
        struct { float zp[4]; float np[4]; } in;
    } sm;
    __shared__ int last_flag;
    __shared__ unsigned long long kbro;
    const int tid = threadIdx.x;

    int pt = blockIdx.x;                 // 0..3359
    int p  = pt / NTILES_;
    int tl = pt % NTILES_;
    int b = p / (C_ - 1);
    int c = p % (C_ - 1) + 1;
    int x0 = (tl % TILES_X_) * TS_;
    int y0 = (tl / TILES_X_) * TS_;

    int n = (int)cnt[pt];
    if (n > CAP_) n = CAP_;
    if (n > 0) {
        {   // zero tile with uint4 stores (2 per thread)
            uint4* t4 = (uint4*)sm.rb.tile;
            t4[tid]       = make_uint4(0u, 0u, 0u, 0u);
            t4[tid + 256] = make_uint4(0u, 0u, 0u, 0u);
        }
        __syncthreads();
        const uint4* lst = lists + (size_t)pt * CAP_;
        int hwv = tid >> 5, ln = tid & 31;   // half-wave per record
        for (int r = hwv; r < n; r += 8) {
            uint4 rec = lst[r];
            int i0 = (int)(rec.y & 0xFFu), i1 = (int)((rec.y >> 8) & 0xFFu);
            float xs = (float)(rec.x & 0xFFFFu);
            float ys = (float)(rec.x >> 16);
            float dnx = __uint_as_float(rec.z);
            float dny = __uint_as_float(rec.w);
            for (int i = i0 + ln; i <= i1; i += 32) {
                float t = (float)(i + 1) * STEP_;
                float cx = __fadd_rn(xs, __fmul_rn(dnx, t));   // identical ops as pass A
                float cy = __fadd_rn(ys, __fmul_rn(dny, t));
                int lx = (int)rintf(cx) - x0;
                int ly = (int)rintf(cy) - y0;
                int cell = ly * TS_ + lx;                      // in-tile by construction
                atomicAdd(&sm.rb.tile[cell >> 1], 1u << ((cell & 1) * 16));
            }
        }
        __syncthreads();
        // conflict-free strided scan: word ix = tid + 256*j (bank = tid%32), cells 2ix,2ix+1
        unsigned bv = 0u; int bi = 0;
        {
            unsigned w0 = sm.rb.tile[tid];
            bv = w0 & 0xFFFFu; bi = tid * 2;
            unsigned hi = w0 >> 16;
            if (hi > bv) { bv = hi; bi = tid * 2 + 1; }
        }
        #pragma unroll
        for (int j = 1; j < 8; ++j) {
            int ix = tid + j * 256;
            unsigned w = sm.rb.tile[ix];
            unsigned lo = w & 0xFFFFu, hi = w >> 16;
            if (lo > bv) { bv = lo; bi = ix * 2; }
            if (hi > bv) { bv = hi; bi = ix * 2 + 1; }
        }
        // 64-lane shuffle argmax (tie -> min idx)
        #pragma unroll
        for (int s = 1; s < 64; s <<= 1) {
            unsigned ov = (unsigned)__shfl_xor((int)bv, s);
            int      oi = __shfl_xor(bi, s);
            if (ov > bv || (ov == bv && oi < bi)) { bv = ov; bi = oi; }
        }
        if ((tid & 63) == 0) { sm.rb.sv[tid >> 6] = bv; sm.rb.si[tid >> 6] = bi; }
        __syncthreads();
        if (tid == 0) {
            unsigned fbv = sm.rb.sv[0]; int fbi = sm.rb.si[0];
            #pragma unroll
            for (int w = 1; w < 4; ++w) {
                unsigned ov = sm.rb.sv[w]; int oi = sm.rb.si[w];
                if (ov > fbv || (ov == fbv && oi < fbi)) { fbv = ov; fbi = oi; }
            }
            int ly = fbi >> 6, lx = fbi & 63;
            unsigned gidx = (unsigned)((y0 + ly) * W_ + (x0 + lx));
            unsigned long long k = ((unsigned long long)fbv << 32)
                                 | (unsigned long long)(0xFFFFFFFFu - gidx);
            atomicMax(&key[b * C_ + c], k);
        }
    }

    // ---- per-plane completion: last-arriver (no waiting) does inlier+finalize ----
    if (tid == 0) {
        __threadfence();                 // release our atomicMax(key) contribution
        unsigned prev = atomicAdd(&pdone[p], 1u);
        last_flag = (prev == (unsigned)(NTILES_ - 1)) ? 1 : 0;
    }
    __syncthreads();
    if (!last_flag) return;
    __threadfence();                     // acquire all 80 blocks' key contributions
    if (tid == 0) kbro = atomicAdd(&key[b * C_ + c], 0ull);   // device-scope read
    __syncthreads();
    unsigned long long k = kbro;
    int pkv = (int)(0xFFFFFFFFu - (unsigned int)(k & 0xFFFFFFFFull));
    float pkx = (float)(pkv % W_), pky = (float)(pkv / W_);

    // inlier accumulation over this plane's compact point list (coalesced)
    int m = (int)cls_cnt[p];
    if (m > P_) m = P_;
    const uint4* cl = cls + (size_t)p * P_;
    float zacc = 0.0f, nacc = 0.0f;
    for (int r = tid; r < m; r += 256) {
        uint4 rec = cl[r];
        float xs = (float)(rec.x & 0xFFFFu);
        float ys = (float)(rec.x >> 16);
        float z   = __uint_as_float(rec.y);
        float dnx = __uint_as_float(rec.z);
        float dny = __uint_as_float(rec.w);
        float dvx = __fsub_rn(pkx, xs), dvy = __fsub_rn(pky, ys);
        float nrm2 = sqrtf(__fadd_rn(__fmul_rn(dvx, dvx), __fmul_rn(dvy, dvy))) + 1e-9f;
        dvx /= nrm2; dvy /= nrm2;
        float dot = __fadd_rn(__fmul_rn(dnx, dvx), __fmul_rn(dny, dvy));
        if (dot > INL_T_) { zacc += z; nacc += 1.0f; }
    }
    #pragma unroll
    for (int s = 1; s < 64; s <<= 1) {
        zacc += __shfl_xor(zacc, s);
        nacc += __shfl_xor(nacc, s);
    }
    if ((tid & 63) == 0) { sm.in.zp[tid >> 6] = zacc; sm.in.np[tid >> 6] = nacc; }
    __syncthreads();
    if (tid != 0) return;

    float zsum_t = sm.in.zp[0] + sm.in.zp[1] + sm.in.zp[2] + sm.in.zp[3];
    float ninl_t = sm.in.np[0] + sm.in.np[1] + sm.in.np[2] + sm.in.np[3];
    float* o = out + (b * C_ + c) * 14;
    bool valid = (counts[b * C_ + c] >= LAB_T_);   // c > 0 always here
    if (!valid) {
        #pragma unroll
        for (int k2 = 0; k2 < 14; ++k2) o[k2] = 0.0f;
        return;
    }
    float depth = zsum_t / fmaxf(ninl_t, 1.0f);
    float z_safe = (fabsf(depth) > 0.001f) ? depth : 1.0f;
    float fx = meta[b * 48 + 0];
    float fy = meta[b * 48 + 4];
    const float* e = extents + c * 3;
    float diam = sqrtf(e[0]*e[0] + e[1]*e[1] + e[2]*e[2]);
    float vmax = (float)(unsigned int)(k >> 32);
    float half_w = ((0.5f * diam) * fx) / z_safe;
    float half_h = ((0.5f * diam) * fy) / z_safe;
    o[0] = (float)b;
    o[1] = (float)c;
    o[2] = pkx - half_w;
    o[3] = pky - half_h;
    o[4] = pkx + half_w;
    o[5] = pky + half_h;
    o[6] = vmax;
    const float* Ki = meta + b * 48 + 9;   // Kinv row-major 3x3
    float rx = Ki[0]*pkx + Ki[1]*pky + Ki[2];
    float ry = Ki[3]*pkx + Ki[4]*pky + Ki[5];
    float rz = Ki[6]*pkx + Ki[7]*pky + Ki[8];
    o[7]  = 1.0f;
    o[8]  = 0.0f;
    o[9]  = 0.0f;
    o[10] = 0.0f;
    o[11] = depth * rx;
    o[12] = depth * ry;
    o[13] = depth * rz;
}

extern "C" void kernel_launch(void* const* d_in, const int* in_sizes, int n_in,
                              void* d_out, int out_size, void* d_ws, size_t ws_size,
                              hipStream_t stream) {
    const int*   label   = (const int*)d_in[0];    // (B,H,W) int32
    const float* vp      = (const float*)d_in[1];  // (B,H,W,66) f32
    const float* extents = (const float*)d_in[2];  // (22,3) f32
    const float* meta    = (const float*)d_in[4];  // (B,48) f32
    float* out = (float*)d_out;                    // (B,C,14) = 616 f32

    char* ws = (char*)d_ws;
    size_t off = 0;
    unsigned int* cnt     = (unsigned int*)(ws + off); off += NPT_ * sizeof(unsigned int);     // 13440
    int*          counts  = (int*)(ws + off);          off += B_ * C_ * sizeof(int);           // +176
    unsigned int* cls_cnt = (unsigned int*)(ws + off); off += NPLANES_ * sizeof(unsigned int); // +168
    unsigned int* pdone   = (unsigned int*)(ws + off); off += NPLANES_ * sizeof(unsigned int); // +168
    size_t zero_bytes = off;                        // 13952 B memset extent
    off = (off + 15) & ~(size_t)15;                 // align 16
    unsigned long long* key = (unsigned long long*)(ws + off);  // init'd by k1 hist block 0
    off += B_ * C_ * sizeof(unsigned long long);
    off = (off + 15) & ~(size_t)15;
    uint4* lists = (uint4*)(ws + off);              // 3360*2048*16B = 110 MB (uninitialized ok)
    off += (size_t)NPT_ * CAP_ * sizeof(uint4);
    uint4* cls = (uint4*)(ws + off);                // 42*15360*16B = 10.3 MB (uninitialized ok)
    off += (size_t)NPLANES_ * P_ * sizeof(uint4);

    hipMemsetAsync(d_ws, 0, zero_bytes, stream);

    binray_count_kernel<<<PA_BLOCKS_ + HIST_BLOCKS_, 256, 0, stream>>>(
        label, vp, cnt, lists, counts, cls_cnt, cls, key, out);
    raster_finalize_kernel<<<NPT_, 256, 0, stream>>>(
        cnt, lists, key, cls, cls_cnt, pdone, counts, extents, meta, out);
}

// Round 5
// 303.025 us; speedup vs baseline: 1.3143x; 1.2556x over previous
//
#include <hip/hip_runtime.h>
#include <math.h>

#define C_      22      // NUM_CLASSES
#define SKIP_   20
#define NSTEP_  200
#define STEP_   4.0f
#define INL_T_  0.9f
#define LAB_T_  500
#define B_      2
#define H_      480
#define W_      640
#define HW_     (H_ * W_)       // 307200
#define P_      (HW_ / SKIP_)   // 15360

#define SUB_A_    25                       // ray segments per point (200/25 = 8 steps each)
#define SEG_LEN_  (NSTEP_ / SUB_A_)        // 8
#define PA_BLOCKS_    ((B_ * P_ * SUB_A_) / 256)  // 3000 ray blocks (768k threads)
#define HIST_BLOCKS_  ((B_ * HW_) / (256 * 4))    // 600 (int4 per thread)
#define INL_BLOCKS_   ((B_ * P_) / 256)           // 120

#define AM_BPP_   64                       // argmax blocks per plane
#define NPLANES_  (B_ * (C_ - 1))          // 42 live planes (c=0 never accumulated)
#define AM_U4PB_  (HW_ / 4 / AM_BPP_)      // 1200 uint4 per argmax block

// key = (count << 32) | (0xFFFFFFFF - idx): max key == max count, tie -> min idx.
// memset-0 init == (count 0, idx 0xFFFFFFFF); every live plane receives 64
// argmax contributions each >= (0, ~cell0), so the 0-init never survives.

// ============================================================================
// Kernel 1: direct hough accumulation (fire-and-forget global atomics)
//           + label histogram (int4).
// No record lists, no atomic-return dependency: each in-bounds ray step does
// one independent atomicAdd into the 54 MB hough array.
// ============================================================================
__global__ __launch_bounds__(256) void bin_hist_kernel(const int* __restrict__ label,
                                                       const float* __restrict__ vp,
                                                       unsigned int* __restrict__ hough,
                                                       int* __restrict__ counts) {
    if (blockIdx.x < PA_BLOCKS_) {
        int tid = blockIdx.x * 256 + threadIdx.x;   // 0 .. B_*P_*SUB_A_-1
        int pt  = tid / SUB_A_;                      // point id (wave spans ~2.5 points)
        int sub = tid - pt * SUB_A_;
        int b   = pt / P_;
        int pi  = pt - b * P_;
        int idx = pi * SKIP_;
        int lab = label[b * HW_ + idx];
        if (lab <= 0) return;
        int xi = idx % W_, yi = idx / W_;
        float xs = (float)xi, ys = (float)yi;
        const float* s = vp + ((size_t)(b * HW_ + idx) * (C_ * 3)) + lab * 3;
        float dx = s[0], dy = s[1];
        float nrm = sqrtf(__fadd_rn(__fmul_rn(dx, dx), __fmul_rn(dy, dy))) + 1e-9f;
        float dnx = dx / nrm, dny = dy / nrm;
        unsigned int* plane = hough + (size_t)(b * C_ + lab) * HW_;
        bool entered = false;
        int iBeg = sub * SEG_LEN_, iEnd = iBeg + SEG_LEN_;
        for (int i = iBeg; i < iEnd; ++i) {
            float t = (float)(i + 1) * STEP_;
            float cx = __fadd_rn(xs, __fmul_rn(dnx, t));   // mul-then-add, no fma
            float cy = __fadd_rn(ys, __fmul_rn(dny, t));
            float cxr = rintf(cx);                          // round-half-even == jnp.round
            float cyr = rintf(cy);
            if (cxr >= 0.0f && cxr <= (float)(W_ - 1) && cyr >= 0.0f && cyr <= (float)(H_ - 1)) {
                int cell = ((int)cyr) * W_ + ((int)cxr);
                atomicAdd(&plane[cell], 1u);                // no return use -> no wait
                entered = true;
            } else if (entered) {
                break;   // in-bounds i-set is an interval (monotone rintf of linear path)
            }
        }
    } else {
        // ---- label histogram, int4-vectorized ----
        __shared__ int h[C_];
        int cb  = blockIdx.x - PA_BLOCKS_;
        const int bpb = HW_ / 1024;          // 300 blocks per image
        int b   = cb / bpb;
        int off = (cb % bpb) * 1024 + threadIdx.x * 4;
        if (threadIdx.x < C_) h[threadIdx.x] = 0;
        __syncthreads();
        int4 l4 = *(const int4*)(label + b * HW_ + off);
        atomicAdd(&h[l4.x], 1);
        atomicAdd(&h[l4.y], 1);
        atomicAdd(&h[l4.z], 1);
        atomicAdd(&h[l4.w], 1);
        __syncthreads();
        if (threadIdx.x < C_) {
            int v = h[threadIdx.x];
            if (v) atomicAdd(&counts[b * C_ + threadIdx.x], v);
        }
    }
}

// ============================================================================
// Kernel 2: streaming argmax over each live plane (uint4 loads) -> key merge.
// ============================================================================
__global__ __launch_bounds__(256) void argmax_kernel(const uint4* __restrict__ hough4,
                                                     unsigned long long* __restrict__ key) {
    __shared__ unsigned long long part[4];
    const int tid = threadIdx.x;
    int p  = blockIdx.x / AM_BPP_;       // 0..41
    int sb = blockIdx.x % AM_BPP_;
    int b = p / (C_ - 1);
    int c = p % (C_ - 1) + 1;
    const uint4* base = hough4 + (size_t)(b * C_ + c) * (HW_ / 4);
    int start = sb * AM_U4PB_;
    unsigned bv = 0u;
    unsigned bi = (unsigned)((start + tid) * 4);   // first inspected cell (zero-plane tie -> min idx)
    for (int r = start + tid; r < start + AM_U4PB_; r += 256) {
        uint4 v4 = base[r];
        unsigned idx0 = (unsigned)(r * 4);
        #pragma unroll
        for (int j = 0; j < 4; ++j) {
            unsigned v = (&v4.x)[j];
            if (v > bv) { bv = v; bi = idx0 + (unsigned)j; }   // strict > keeps min idx
        }
    }
    unsigned long long k = ((unsigned long long)bv << 32)
                         | (unsigned long long)(0xFFFFFFFFu - bi);
    #pragma unroll
    for (int s = 1; s < 64; s <<= 1) {
        unsigned long long ok = __shfl_xor(k, s);
        if (ok > k) k = ok;
    }
    if ((tid & 63) == 0) part[tid >> 6] = k;
    __syncthreads();
    if (tid == 0) {
        unsigned long long km = part[0];
        #pragma unroll
        for (int w = 1; w < 4; ++w) if (part[w] > km) km = part[w];
        atomicMax(&key[b * C_ + c], km);
    }
}

// ============================================================================
// Kernel 3 (verbatim Round-2 proven): inlier z/count accumulation + last-block
// finalize via done-counter (no waiting).
// ============================================================================
__global__ __launch_bounds__(256) void inlier_finalize_kernel(const int* __restrict__ label,
                                                              const float* __restrict__ vp,
                                                              const unsigned long long* __restrict__ key,
                                                              float* __restrict__ z_sum,
                                                              float* __restrict__ n_inl,
                                                              int* __restrict__ counts,
                                                              const float* __restrict__ extents,
                                                              const float* __restrict__ meta,
                                                              unsigned int* __restrict__ done,
                                                              float* __restrict__ out) {
    __shared__ float zs[C_];
    __shared__ float ns[C_];
    __shared__ int last_flag;
    const int bpb = P_ / 256;
    int b  = blockIdx.x / bpb;
    int pi = (blockIdx.x % bpb) * 256 + threadIdx.x;
    if (threadIdx.x < C_) { zs[threadIdx.x] = 0.0f; ns[threadIdx.x] = 0.0f; }
    __syncthreads();
    int idx = pi * SKIP_;
    int lab = label[b * HW_ + idx];
    if (lab > 0) {
        float ys = (float)(idx / W_);
        float xs = (float)(idx % W_);
        const float* s = vp + ((size_t)(b * HW_ + idx) * (C_ * 3)) + lab * 3;
        float dx = s[0], dy = s[1], z = s[2];
        float nrm = sqrtf(__fadd_rn(__fmul_rn(dx, dx), __fmul_rn(dy, dy))) + 1e-9f;
        float dnx = dx / nrm, dny = dy / nrm;
        unsigned long long k = key[b * C_ + lab];
        int pkv = (int)(0xFFFFFFFFu - (unsigned int)(k & 0xFFFFFFFFull));
        float pkx = (float)(pkv % W_), pky = (float)(pkv / W_);
        float dvx = __fsub_rn(pkx, xs), dvy = __fsub_rn(pky, ys);
        float nrm2 = sqrtf(__fadd_rn(__fmul_rn(dvx, dvx), __fmul_rn(dvy, dvy))) + 1e-9f;
        dvx /= nrm2; dvy /= nrm2;
        float dot = __fadd_rn(__fmul_rn(dnx, dvx), __fmul_rn(dny, dvy));
        if (dot > INL_T_) {
            atomicAdd(&zs[lab], z);
            atomicAdd(&ns[lab], 1.0f);
        }
    }
    __syncthreads();
    if (threadIdx.x < C_) {
        if (ns[threadIdx.x] != 0.0f) {
            atomicAdd(&z_sum[b * C_ + threadIdx.x], zs[threadIdx.x]);
            atomicAdd(&n_inl[b * C_ + threadIdx.x], ns[threadIdx.x]);
        }
    }
    // ---- completion count: last block runs finalize ----
    if (threadIdx.x == 0) {
        __threadfence();   // release our z_sum/n_inl contributions
        unsigned prev = atomicAdd(done, 1u);
        last_flag = (prev == (unsigned)(INL_BLOCKS_ - 1)) ? 1 : 0;
    }
    __syncthreads();
    if (!last_flag) return;
    __threadfence();       // acquire all other blocks' contributions
    int t = threadIdx.x;
    if (t >= B_ * C_) return;
    int bb = t / C_, c = t % C_;
    float* o = out + t * 14;
    // device-scope atomic reads: avoid any stale-cache hazard across XCDs
    int   cnt_t  = atomicAdd(&counts[t], 0);
    float zsum_t = atomicAdd(&z_sum[t], 0.0f);
    float ninl_t = atomicAdd(&n_inl[t], 0.0f);
    unsigned long long k = atomicAdd((unsigned long long*)&key[0] + t, 0ull);
    bool valid = (cnt_t >= LAB_T_) && (c > 0);
    if (!valid) {
        #pragma unroll
        for (int k2 = 0; k2 < 14; ++k2) o[k2] = 0.0f;
        return;
    }
    float depth = zsum_t / fmaxf(ninl_t, 1.0f);
    float z_safe = (fabsf(depth) > 0.001f) ? depth : 1.0f;
    float fx = meta[bb * 48 + 0];
    float fy = meta[bb * 48 + 4];
    const float* e = extents + c * 3;
    float diam = sqrtf(e[0]*e[0] + e[1]*e[1] + e[2]*e[2]);
    float vmax = (float)(unsigned int)(k >> 32);
    int pkv = (int)(0xFFFFFFFFu - (unsigned int)(k & 0xFFFFFFFFull));
    float pkx = (float)(pkv % W_), pky = (float)(pkv / W_);
    float half_w = ((0.5f * diam) * fx) / z_safe;
    float half_h = ((0.5f * diam) * fy) / z_safe;
    o[0] = (float)bb;
    o[1] = (float)c;
    o[2] = pkx - half_w;
    o[3] = pky - half_h;
    o[4] = pkx + half_w;
    o[5] = pky + half_h;
    o[6] = vmax;
    const float* Ki = meta + bb * 48 + 9;   // Kinv row-major 3x3
    float rx = Ki[0]*pkx + Ki[1]*pky + Ki[2];
    float ry = Ki[3]*pkx + Ki[4]*pky + Ki[5];
    float rz = Ki[6]*pkx + Ki[7]*pky + Ki[8];
    o[7]  = 1.0f;
    o[8]  = 0.0f;
    o[9]  = 0.0f;
    o[10] = 0.0f;
    o[11] = depth * rx;
    o[12] = depth * ry;
    o[13] = depth * rz;
}

extern "C" void kernel_launch(void* const* d_in, const int* in_sizes, int n_in,
                              void* d_out, int out_size, void* d_ws, size_t ws_size,
                              hipStream_t stream) {
    const int*   label   = (const int*)d_in[0];    // (B,H,W) int32
    const float* vp      = (const float*)d_in[1];  // (B,H,W,66) f32
    const float* extents = (const float*)d_in[2];  // (22,3) f32
    const float* meta    = (const float*)d_in[4];  // (B,48) f32
    float* out = (float*)d_out;                    // (B,C,14) = 616 f32

    char* ws = (char*)d_ws;
    size_t off = 0;
    unsigned int* hough = (unsigned int*)(ws + off);
    off += (size_t)B_ * C_ * HW_ * sizeof(unsigned int);        // 54,067,200 B
    int*   counts = (int*)(ws + off);   off += B_ * C_ * sizeof(int);     // +176
    float* z_sum  = (float*)(ws + off); off += B_ * C_ * sizeof(float);   // +176
    float* n_inl  = (float*)(ws + off); off += B_ * C_ * sizeof(float);   // +176
    unsigned int* done = (unsigned int*)(ws + off); off += sizeof(unsigned int); // +4
    off = (off + 7) & ~(size_t)7;                   // align 8
    unsigned long long* key = (unsigned long long*)(ws + off);  // 0-init valid under encoding
    off += B_ * C_ * sizeof(unsigned long long);                // +352
    size_t zero_bytes = off;                        // ~54.07 MB, one memset

    hipMemsetAsync(d_ws, 0, zero_bytes, stream);

    bin_hist_kernel<<<PA_BLOCKS_ + HIST_BLOCKS_, 256, 0, stream>>>(label, vp, hough, counts);
    argmax_kernel<<<NPLANES_ * AM_BPP_, 256, 0, stream>>>((const uint4*)hough, key);
    inlier_finalize_kernel<<<INL_BLOCKS_, 256, 0, stream>>>(label, vp, key, z_sum, n_inl,
                                                            counts, extents, meta, done, out);
}

// Round 6
// 257.596 us; speedup vs baseline: 1.5461x; 1.1764x over previous
//
#include <hip/hip_runtime.h>
#include <math.h>

#define C_      22      // NUM_CLASSES
#define SKIP_   20
#define NSTEP_  200
#define STEP_   4.0f
#define INL_T_  0.9f
#define LAB_T_  500
#define B_      2
#define H_      480
#define W_      640
#define HW_     (H_ * W_)       // 307200
#define P_      (HW_ / SKIP_)   // 15360
#define NPTS_   (B_ * P_)       // 30720

#define TS_       64            // spatial tile side
#define TILES_X_  (W_ / TS_)    // 10
#define NTILES_Y_ 8             // covers y 0..511 (exact check restricts to 479)
#define NTILES_   (TILES_X_ * NTILES_Y_)   // 80
#define NPLANES_  (B_ * (C_ - 1))          // 42 live planes (c=0 dead)
#define NPT_      (NPLANES_ * NTILES_)     // 3360 plane-tiles

#define CMP_BLOCKS_   (NPTS_ / 256)               // 120 compaction blocks
#define HIST_BLOCKS_  ((B_ * HW_) / (256 * 4))    // 600 (int4 per thread)

#define KEY_INIT_ 0x00000000FFFFFFFFull    // (count 0, idx 0) under the key encoding

// ============================================================================
// Kernel 1: per-plane point compaction (LDS-aggregated, ~5k global atomics)
//           + label histogram (int4) + key init.
// Record: {x|y<<16, z, dnx, dny} — the only data later passes need.
// ============================================================================
__global__ __launch_bounds__(256) void compact_hist_kernel(const int* __restrict__ label,
                                                           const float* __restrict__ vp,
                                                           unsigned int* __restrict__ cls_cnt,
                                                           uint4* __restrict__ cls,
                                                           int* __restrict__ counts,
                                                           unsigned long long* __restrict__ key) {
    const int tid = threadIdx.x;
    if (blockIdx.x < CMP_BLOCKS_) {
        __shared__ int hcnt[NPLANES_];
        __shared__ int hbase[NPLANES_];
        for (int i = tid; i < NPLANES_; i += 256) hcnt[i] = 0;
        __syncthreads();
        int g   = blockIdx.x * 256 + tid;    // 0..NPTS_-1
        int b   = g / P_;
        int pi  = g - b * P_;
        int idx = pi * SKIP_;
        int lab = label[b * HW_ + idx];
        int p = -1, slot = 0;
        uint4 r;
        if (lab > 0) {
            int xi = idx % W_, yi = idx / W_;
            const float* s = vp + ((size_t)(b * HW_ + idx) * (C_ * 3)) + lab * 3;
            float dx = s[0], dy = s[1], z = s[2];
            float nrm = sqrtf(__fadd_rn(__fmul_rn(dx, dx), __fmul_rn(dy, dy))) + 1e-9f;
            float dnx = dx / nrm, dny = dy / nrm;
            p = b * (C_ - 1) + (lab - 1);
            r.x = (unsigned)xi | ((unsigned)yi << 16);
            r.y = __float_as_uint(z);
            r.z = __float_as_uint(dnx);
            r.w = __float_as_uint(dny);
            slot = atomicAdd(&hcnt[p], 1);
        }
        __syncthreads();
        for (int i = tid; i < NPLANES_; i += 256) {
            int v = hcnt[i];
            hbase[i] = v ? (int)atomicAdd(&cls_cnt[i], (unsigned)v) : 0;
        }
        __syncthreads();
        if (p >= 0)
            cls[(size_t)p * P_ + hbase[p] + slot] = r;   // base+slot < P_ by construction
    } else {
        // ---- label histogram, int4-vectorized (+ block 0: key init) ----
        __shared__ int h[C_];
        int cb  = blockIdx.x - CMP_BLOCKS_;
        if (cb == 0 && tid < B_ * C_)
            key[tid] = KEY_INIT_;            // visible to k2 via stream ordering
        const int bpb = HW_ / 1024;          // 300 blocks per image
        int b   = cb / bpb;
        int off = (cb % bpb) * 1024 + tid * 4;
        if (tid < C_) h[tid] = 0;
        __syncthreads();
        int4 l4 = *(const int4*)(label + b * HW_ + off);
        atomicAdd(&h[l4.x], 1);
        atomicAdd(&h[l4.y], 1);
        atomicAdd(&h[l4.z], 1);
        atomicAdd(&h[l4.w], 1);
        __syncthreads();
        if (tid < C_) {
            int v = h[tid];
            if (v) atomicAdd(&counts[b * C_ + tid], v);
        }
    }
}

// ============================================================================
// Kernel 2: analytic ray->tile rasterize + argmax, one block per plane-tile.
// Conservative interval (widened +-0.51 px, +-2 steps) -> exact per-step check
// with bit-identical float ops; each in-image step votes in exactly one tile.
// key = (count << 32) | (0xFFFFFFFF - idx): max key == max count, tie -> min idx.
// ============================================================================
__global__ __launch_bounds__(256) void raster_argmax_kernel(const uint4* __restrict__ cls,
                                                            const unsigned int* __restrict__ cls_cnt,
                                                            unsigned long long* __restrict__ key) {
    __shared__ unsigned int tile[TS_ * TS_ / 2];   // u16-packed, 8 KB
    __shared__ unsigned int sv[4];
    __shared__ int          si[4];
    const int tid = threadIdx.x;
    int pt = blockIdx.x;                 // 0..3359
    int p  = pt / NTILES_;
    int tl = pt % NTILES_;
    int b = p / (C_ - 1);
    int c = p % (C_ - 1) + 1;
    int x0 = (tl % TILES_X_) * TS_;
    int y0 = (tl / TILES_X_) * TS_;
    {   // zero tile with uint4 stores (2 per thread)
        uint4* t4 = (uint4*)tile;
        t4[tid]       = make_uint4(0u, 0u, 0u, 0u);
        t4[tid + 256] = make_uint4(0u, 0u, 0u, 0u);
    }
    __syncthreads();

    int m = (int)cls_cnt[p];
    if (m > P_) m = P_;
    const uint4* cl = cls + (size_t)p * P_;
    const float lox = (float)x0 - 0.51f, hix = (float)x0 + 63.51f;
    const float loy = (float)y0 - 0.51f, hiy = (float)y0 + 63.51f;
    for (int rI = tid; rI < m; rI += 256) {
        uint4 rec = cl[rI];
        float xs  = (float)(rec.x & 0xFFFFu);
        float ys  = (float)(rec.x >> 16);
        float dnx = __uint_as_float(rec.z);
        float dny = __uint_as_float(rec.w);
        float tLo = STEP_, tHi = (float)NSTEP_ * STEP_;
        bool empty = false;
        if (fabsf(dnx) > 1e-8f) {
            float ta = (lox - xs) / dnx, tb = (hix - xs) / dnx;
            float t1 = fminf(ta, tb), t2 = fmaxf(ta, tb);
            tLo = fmaxf(tLo, t1); tHi = fminf(tHi, t2);
        } else if (xs < lox || xs > hix) { empty = true; }
        if (fabsf(dny) > 1e-8f) {
            float ta = (loy - ys) / dny, tb = (hiy - ys) / dny;
            float t1 = fminf(ta, tb), t2 = fmaxf(ta, tb);
            tLo = fmaxf(tLo, t1); tHi = fminf(tHi, t2);
        } else if (ys < loy || ys > hiy) { empty = true; }
        if (empty || tLo > tHi) continue;
        int iB = (int)floorf(tLo * 0.25f) - 2; if (iB < 0) iB = 0;
        int iE = (int)ceilf(tHi * 0.25f) + 2;  if (iE > NSTEP_ - 1) iE = NSTEP_ - 1;
        for (int i = iB; i <= iE; ++i) {
            float t = (float)(i + 1) * STEP_;
            float cx = __fadd_rn(xs, __fmul_rn(dnx, t));   // bit-identical to reference path
            float cy = __fadd_rn(ys, __fmul_rn(dny, t));
            float cxr = rintf(cx);                          // round-half-even == jnp.round
            float cyr = rintf(cy);
            if (cxr >= 0.0f && cxr <= (float)(W_ - 1) && cyr >= 0.0f && cyr <= (float)(H_ - 1)) {
                int lx = (int)cxr - x0;
                int ly = (int)cyr - y0;
                if ((unsigned)lx < TS_ && (unsigned)ly < TS_) {
                    int cell = ly * TS_ + lx;
                    atomicAdd(&tile[cell >> 1], 1u << ((cell & 1) * 16));
                }
            }
        }
    }
    __syncthreads();
    // conflict-free strided scan: word ix = tid + 256*j (bank = tid%32), cells 2ix,2ix+1
    unsigned bv = 0u; int bi = 0;
    {
        unsigned w0 = tile[tid];
        bv = w0 & 0xFFFFu; bi = tid * 2;
        unsigned hi = w0 >> 16;
        if (hi > bv) { bv = hi; bi = tid * 2 + 1; }
    }
    #pragma unroll
    for (int j = 1; j < 8; ++j) {
        int ix = tid + j * 256;
        unsigned w = tile[ix];
        unsigned lo = w & 0xFFFFu, hi = w >> 16;
        if (lo > bv) { bv = lo; bi = ix * 2; }
        if (hi > bv) { bv = hi; bi = ix * 2 + 1; }
    }
    // 64-lane shuffle argmax (tie -> min local idx; local idx order == global idx order)
    #pragma unroll
    for (int s = 1; s < 64; s <<= 1) {
        unsigned ov = (unsigned)__shfl_xor((int)bv, s);
        int      oi = __shfl_xor(bi, s);
        if (ov > bv || (ov == bv && oi < bi)) { bv = ov; bi = oi; }
    }
    if ((tid & 63) == 0) { sv[tid >> 6] = bv; si[tid >> 6] = bi; }
    __syncthreads();
    if (tid == 0) {
        unsigned fbv = sv[0]; int fbi = si[0];
        #pragma unroll
        for (int w = 1; w < 4; ++w) {
            unsigned ov = sv[w]; int oi = si[w];
            if (ov > fbv || (ov == fbv && oi < fbi)) { fbv = ov; fbi = oi; }
        }
        if (fbv > 0u) {   // zero-vote tile can never beat KEY_INIT (count0,idx0)
            int ly = fbi >> 6, lx = fbi & 63;
            unsigned gidx = (unsigned)((y0 + ly) * W_ + (x0 + lx));
            unsigned long long k = ((unsigned long long)fbv << 32)
                                 | (unsigned long long)(0xFFFFFFFFu - gidx);
            atomicMax(&key[b * C_ + c], k);
        }
    }
}

// ============================================================================
// Kernel 3: one block per plane — inlier reduce over the compact list
// (coalesced), plain store of z_sum/n_inl, last-arriver finalizes all 44 rows.
// ============================================================================
__global__ __launch_bounds__(256) void inlier_finalize_kernel(const uint4* __restrict__ cls,
                                                              const unsigned int* __restrict__ cls_cnt,
                                                              const unsigned long long* __restrict__ key,
                                                              float* __restrict__ z_sum,
                                                              float* __restrict__ n_inl,
                                                              int* __restrict__ counts,
                                                              const float* __restrict__ extents,
                                                              const float* __restrict__ meta,
                                                              unsigned int* __restrict__ done,
                                                              float* __restrict__ out) {
    __shared__ float zp[4];
    __shared__ float np[4];
    __shared__ int last_flag;
    const int tid = threadIdx.x;
    int p = blockIdx.x;                  // 0..41
    int b = p / (C_ - 1);
    int c = p % (C_ - 1) + 1;
    int t_ = b * C_ + c;
    unsigned long long kp = key[t_];     // stream-ordered after k2
    int pkv = (int)(0xFFFFFFFFu - (unsigned int)(kp & 0xFFFFFFFFull));
    float pkx = (float)(pkv % W_), pky = (float)(pkv / W_);
    int m = (int)cls_cnt[p];
    if (m > P_) m = P_;
    const uint4* cl = cls + (size_t)p * P_;
    float zacc = 0.0f, nacc = 0.0f;
    for (int r = tid; r < m; r += 256) {
        uint4 rec = cl[r];
        float xs  = (float)(rec.x & 0xFFFFu);
        float ys  = (float)(rec.x >> 16);
        float z   = __uint_as_float(rec.y);
        float dnx = __uint_as_float(rec.z);
        float dny = __uint_as_float(rec.w);
        float dvx = __fsub_rn(pkx, xs), dvy = __fsub_rn(pky, ys);
        float nrm2 = sqrtf(__fadd_rn(__fmul_rn(dvx, dvx), __fmul_rn(dvy, dvy))) + 1e-9f;
        dvx /= nrm2; dvy /= nrm2;
        float dot = __fadd_rn(__fmul_rn(dnx, dvx), __fmul_rn(dny, dvy));
        if (dot > INL_T_) { zacc += z; nacc += 1.0f; }
    }
    #pragma unroll
    for (int s = 1; s < 64; s <<= 1) {
        zacc += __shfl_xor(zacc, s);
        nacc += __shfl_xor(nacc, s);
    }
    if ((tid & 63) == 0) { zp[tid >> 6] = zacc; np[tid >> 6] = nacc; }
    __syncthreads();
    if (tid == 0) {
        z_sum[t_] = zp[0] + zp[1] + zp[2] + zp[3];
        n_inl[t_] = np[0] + np[1] + np[2] + np[3];
        __threadfence();                 // release before completion signal
        unsigned prev = atomicAdd(done, 1u);
        last_flag = (prev == (unsigned)(NPLANES_ - 1)) ? 1 : 0;
    }
    __syncthreads();
    if (!last_flag) return;
    __threadfence();                     // acquire all planes' stores
    int t = tid;
    if (t >= B_ * C_) return;
    int bb = t / C_, c2 = t % C_;
    float* o = out + t * 14;
    // device-scope atomic reads: avoid any stale-cache hazard across XCDs
    int   cnt_t  = atomicAdd(&counts[t], 0);
    bool valid = (cnt_t >= LAB_T_) && (c2 > 0);
    if (!valid) {
        #pragma unroll
        for (int k2 = 0; k2 < 14; ++k2) o[k2] = 0.0f;
        return;
    }
    float zsum_t = atomicAdd(&z_sum[t], 0.0f);
    float ninl_t = atomicAdd(&n_inl[t], 0.0f);
    unsigned long long k = atomicAdd((unsigned long long*)&key[0] + t, 0ull);
    float depth = zsum_t / fmaxf(ninl_t, 1.0f);
    float z_safe = (fabsf(depth) > 0.001f) ? depth : 1.0f;
    float fx = meta[bb * 48 + 0];
    float fy = meta[bb * 48 + 4];
    const float* e = extents + c2 * 3;
    float diam = sqrtf(e[0]*e[0] + e[1]*e[1] + e[2]*e[2]);
    float vmax = (float)(unsigned int)(k >> 32);
    int pkv2 = (int)(0xFFFFFFFFu - (unsigned int)(k & 0xFFFFFFFFull));
    float pkx2 = (float)(pkv2 % W_), pky2 = (float)(pkv2 / W_);
    float half_w = ((0.5f * diam) * fx) / z_safe;
    float half_h = ((0.5f * diam) * fy) / z_safe;
    o[0] = (float)bb;
    o[1] = (float)c2;
    o[2] = pkx2 - half_w;
    o[3] = pky2 - half_h;
    o[4] = pkx2 + half_w;
    o[5] = pky2 + half_h;
    o[6] = vmax;
    const float* Ki = meta + bb * 48 + 9;   // Kinv row-major 3x3
    float rx = Ki[0]*pkx2 + Ki[1]*pky2 + Ki[2];
    float ry = Ki[3]*pkx2 + Ki[4]*pky2 + Ki[5];
    float rz = Ki[6]*pkx2 + Ki[7]*pky2 + Ki[8];
    o[7]  = 1.0f;
    o[8]  = 0.0f;
    o[9]  = 0.0f;
    o[10] = 0.0f;
    o[11] = depth * rx;
    o[12] = depth * ry;
    o[13] = depth * rz;
}

extern "C" void kernel_launch(void* const* d_in, const int* in_sizes, int n_in,
                              void* d_out, int out_size, void* d_ws, size_t ws_size,
                              hipStream_t stream) {
    const int*   label   = (const int*)d_in[0];    // (B,H,W) int32
    const float* vp      = (const float*)d_in[1];  // (B,H,W,66) f32
    const float* extents = (const float*)d_in[2];  // (22,3) f32
    const float* meta    = (const float*)d_in[4];  // (B,48) f32
    float* out = (float*)d_out;                    // (B,C,14) = 616 f32

    char* ws = (char*)d_ws;
    size_t off = 0;
    unsigned int* cls_cnt = (unsigned int*)(ws + off); off += NPLANES_ * sizeof(unsigned int); // 168
    int*          counts  = (int*)(ws + off);          off += B_ * C_ * sizeof(int);           // +176
    unsigned int* done    = (unsigned int*)(ws + off); off += sizeof(unsigned int);            // +4
    size_t zero_bytes = off;                        // 348 B memset extent
    off = (off + 15) & ~(size_t)15;                 // align 16
    float* z_sum  = (float*)(ws + off); off += B_ * C_ * sizeof(float);   // plain-stored, no init
    float* n_inl  = (float*)(ws + off); off += B_ * C_ * sizeof(float);
    off = (off + 15) & ~(size_t)15;
    unsigned long long* key = (unsigned long long*)(ws + off);  // init'd by k1 hist block 0
    off += B_ * C_ * sizeof(unsigned long long);
    off = (off + 15) & ~(size_t)15;
    uint4* cls = (uint4*)(ws + off);                // 42*15360*16B = 10.3 MB (uninitialized ok)
    off += (size_t)NPLANES_ * P_ * sizeof(uint4);

    hipMemsetAsync(d_ws, 0, zero_bytes, stream);

    compact_hist_kernel<<<CMP_BLOCKS_ + HIST_BLOCKS_, 256, 0, stream>>>(
        label, vp, cls_cnt, cls, counts, key);
    raster_argmax_kernel<<<NPT_, 256, 0, stream>>>(cls, cls_cnt, key);
    inlier_finalize_kernel<<<NPLANES_, 256, 0, stream>>>(
        cls, cls_cnt, key, z_sum, n_inl, counts, extents, meta, done, out);
}